// Round 1
// baseline (448.091 us; speedup 1.0000x reference)
//
#include <hip/hip_runtime.h>

// LocalAffinity: out[b,k,t,z,y,x] = x[b,k,z,y,x] - x[b,k, clamp(z+dz), clamp(y+dy), clamp(x+dx)]
// taps t: 26 offsets (raster (i,j,k) in {0,1,2}^3 minus center) at dilation 1, then same at dilation 2.
// Shapes fixed by the reference: B=1, K=2, D=64, H=128, W=128. Output 436 MB fp32 -> HBM-write-bound.

constexpr int Kc  = 2;
constexpr int Dz  = 64;
constexpr int Hy  = 128;
constexpr int Wx  = 128;
constexpr int DHW = Dz * Hy * Wx;      // 1048576
constexpr int TAPS = 52;

typedef float floatx4 __attribute__((ext_vector_type(4)));

__global__ __launch_bounds__(256)
void LocalAffinity_kernel(const float* __restrict__ in, float* __restrict__ out) {
    const int tid = blockIdx.x * blockDim.x + threadIdx.x;
    // mapping: x4 (W/4=32) fastest, then y (128), z (64), k (2)
    const int x4 = tid & 31;
    const int y  = (tid >> 5) & 127;
    const int z  = (tid >> 12) & 63;
    const int kk = tid >> 18;
    const int x0 = x4 << 2;

    const float* __restrict__ base = in + kk * DHW;
    const float* crow = base + (z * Hy + y) * Wx + x0;
    const float c0 = crow[0], c1 = crow[1], c2 = crow[2], c3 = crow[3];

    float* obase = out + (size_t)kk * ((size_t)TAPS * DHW) + (size_t)(z * Hy + y) * Wx + x0;

    #pragma unroll
    for (int t = 0; t < TAPS; ++t) {
        const int d   = (t < 26) ? 1 : 2;
        const int tt  = (t < 26) ? t : t - 26;
        const int idx = (tt < 13) ? tt : tt + 1;       // skip center (1,1,1) = raster idx 13
        const int di  = idx / 9 - 1;                   // dz direction
        const int dj  = (idx / 3) % 3 - 1;             // dy direction
        const int dk  = idx % 3 - 1;                   // dx direction

        const int zc = min(max(z + di * d, 0), Dz - 1);
        const int yc = min(max(y + dj * d, 0), Hy - 1);
        const float* row = base + (zc * Hy + yc) * Wx;

        const int xb = x0 + dk * d;
        const int xa0 = min(max(xb + 0, 0), Wx - 1);
        const int xa1 = min(max(xb + 1, 0), Wx - 1);
        const int xa2 = min(max(xb + 2, 0), Wx - 1);
        const int xa3 = min(max(xb + 3, 0), Wx - 1);

        floatx4 o;
        o.x = c0 - row[xa0];
        o.y = c1 - row[xa1];
        o.z = c2 - row[xa2];
        o.w = c3 - row[xa3];

        __builtin_nontemporal_store(o, (floatx4*)(obase + (size_t)t * DHW));
    }
}

extern "C" void kernel_launch(void* const* d_in, const int* in_sizes, int n_in,
                              void* d_out, int out_size, void* d_ws, size_t ws_size,
                              hipStream_t stream) {
    const float* x = (const float*)d_in[0];
    float* out = (float*)d_out;
    const int total = Kc * Dz * Hy * (Wx / 4);   // 524288 threads
    const int block = 256;
    const int grid = total / block;              // 2048 blocks
    LocalAffinity_kernel<<<grid, block, 0, stream>>>(x, out);
}

// Round 2
// 429.703 us; speedup vs baseline: 1.0428x; 1.0428x over previous
//
#include <hip/hip_runtime.h>

// LocalAffinity: out[k,t,z,y,x] = x[k,z,y,x] - x[k, clamp(z+di*d), clamp(y+dj*d), clamp(x+dk*d)]
// 26 taps (raster (i,j,k) minus center) at d=1 then d=2. B=1,K=2,D=64,H=128,W=128.
// HBM-write-bound: 436 MB out. Strategy: 17 coalesced float4 row loads/thread,
// x-shifts via wave shuffles, XCD-pinned z-slabs for L2-resident input.

constexpr int Dz  = 64;
constexpr int Hy  = 128;
constexpr int Wx  = 128;
constexpr int DHW = Dz * Hy * Wx;      // 1048576
constexpr int TAPS = 52;

typedef float floatx4 __attribute__((ext_vector_type(4)));

__device__ __forceinline__ int iclamp(int v, int hi) { return v < 0 ? 0 : (v > hi ? hi : v); }

__global__ __launch_bounds__(256)
void LocalAffinity_kernel(const float* __restrict__ in, float* __restrict__ out) {
    // Block swizzle: slab = blockIdx % 16 -> (k, z-octet); round-robin XCD = blockIdx % 8
    // pins each 1.2 MB slab (8 z-slices + halo) to one XCD L2.
    const int b    = blockIdx.x;
    const int slab = b & 15;           // kk*8 + z-octet
    const int w    = b >> 4;           // 0..127 within slab
    const int kk   = slab >> 3;
    const int z    = ((slab & 7) << 3) | (w >> 4);
    const int idx  = ((w & 15) << 8) | threadIdx.x;   // 0..4095 over (y, x4)
    const int y    = idx >> 5;
    const int x4   = idx & 31;
    const int x0   = x4 << 2;

    const float* __restrict__ base = in + kk * DHW;
    const floatx4 c = *(const floatx4*)(base + (z * Hy + y) * Wx + x0);

    float* obase = out + (size_t)kk * ((size_t)TAPS * DHW) + (size_t)((z * Hy + y) * Wx + x0);

    #pragma unroll
    for (int dd = 1; dd <= 2; ++dd) {
        #pragma unroll
        for (int di = -1; di <= 1; ++di) {
            #pragma unroll
            for (int dj = -1; dj <= 1; ++dj) {
                floatx4 v;
                if (di == 0 && dj == 0) {
                    v = c;
                } else {
                    const int zc = iclamp(z + di * dd, Dz - 1);
                    const int yc = iclamp(y + dj * dd, Hy - 1);
                    v = *(const floatx4*)(base + (zc * Hy + yc) * Wx + x0);
                }
                #pragma unroll
                for (int dk = -1; dk <= 1; ++dk) {
                    if (di == 0 && dj == 0 && dk == 0) continue;
                    const int raster = (di + 1) * 9 + (dj + 1) * 3 + (dk + 1);
                    const int t26    = raster < 13 ? raster : raster - 1;
                    const int t      = t26 + (dd == 1 ? 0 : 26);

                    floatx4 s;
                    if (dk == 0) {
                        s = v;
                    } else if (dk < 0) {
                        if (dd == 1) {
                            float sm = __shfl_up(v.w, 1);
                            sm = (x4 == 0) ? v.x : sm;     // x-clamp at left edge
                            s.x = sm; s.y = v.x; s.z = v.y; s.w = v.z;
                        } else {
                            float a  = __shfl_up(v.z, 1);
                            float bb = __shfl_up(v.w, 1);
                            a  = (x4 == 0) ? v.x : a;
                            bb = (x4 == 0) ? v.x : bb;
                            s.x = a; s.y = bb; s.z = v.x; s.w = v.y;
                        }
                    } else {
                        if (dd == 1) {
                            float sp = __shfl_down(v.x, 1);
                            sp = (x4 == 31) ? v.w : sp;    // x-clamp at right edge
                            s.x = v.y; s.y = v.z; s.z = v.w; s.w = sp;
                        } else {
                            float a  = __shfl_down(v.x, 1);
                            float bb = __shfl_down(v.y, 1);
                            a  = (x4 == 31) ? v.w : a;
                            bb = (x4 == 31) ? v.w : bb;
                            s.x = v.z; s.y = v.w; s.z = a; s.w = bb;
                        }
                    }

                    floatx4 o;
                    o.x = c.x - s.x; o.y = c.y - s.y; o.z = c.z - s.z; o.w = c.w - s.w;
                    __builtin_nontemporal_store(o, (floatx4*)(obase + (size_t)t * DHW));
                }
            }
        }
    }
}

extern "C" void kernel_launch(void* const* d_in, const int* in_sizes, int n_in,
                              void* d_out, int out_size, void* d_ws, size_t ws_size,
                              hipStream_t stream) {
    const float* x = (const float*)d_in[0];
    float* out = (float*)d_out;
    LocalAffinity_kernel<<<2048, 256, 0, stream>>>(x, out);
}